// Round 4
// baseline (797.196 us; speedup 1.0000x reference)
//
#include <hip/hip_runtime.h>
#include <hip/hip_bf16.h>
#include <cstdint>
#include <cstddef>

typedef __hip_bfloat16 bf16;
typedef short bf16x8 __attribute__((ext_vector_type(8)));
typedef float f32x4 __attribute__((ext_vector_type(4)));

#define MFMA(a, b, c) __builtin_amdgcn_mfma_f32_16x16x32_bf16((a), (b), (c), 0, 0, 0)

// ---------------------------------------------------------------------------
// K0: all three weight transposes in one launch (grid 1024).
// ---------------------------------------------------------------------------
__global__ __launch_bounds__(256) void wtrans_k(const float* __restrict__ wq,
                                                const float* __restrict__ wkv,
                                                const float* __restrict__ wp,
                                                bf16* __restrict__ wqT,
                                                bf16* __restrict__ wkvT,
                                                bf16* __restrict__ wpT) {
  int idx = blockIdx.x * 256 + threadIdx.x;
  if (idx < 65536) {
    int n = idx >> 8, k = idx & 255;
    wqT[idx] = __float2bfloat16(wq[k * 256 + n]);
  } else if (idx < 196608) {
    int i = idx - 65536;
    int n = i >> 8, k = i & 255;
    wkvT[i] = __float2bfloat16(wkv[k * 512 + n]);
  } else {
    int i = idx - 196608;
    int n = i >> 8, k = i & 255;
    wpT[i] = __float2bfloat16(wp[k * 256 + n]);
  }
}

// ---------------------------------------------------------------------------
// T1: q gather-transpose: f32 NCHW (one batch) -> bf16 WINDOW-MAJOR qwM[sw][t][c].
// ---------------------------------------------------------------------------
__global__ __launch_bounds__(256) void t_winq_k(const float* __restrict__ src,
                                                bf16* __restrict__ dst,
                                                int hw0, int swoff) {
  __shared__ bf16 T[64][66];
  int tile = blockIdx.x;
  int c0 = (tile & 3) << 6;
  int hwb = hw0 + ((tile >> 2) << 6);
  int tid = threadIdx.x;
  {
    int hwl = tid & 63, cb = tid >> 6;
    const float* s = src + (size_t)(c0 + cb) * 65536 + hwb + hwl;
#pragma unroll
    for (int i = 0; i < 16; ++i)
      T[cb + i * 4][hwl] = __float2bfloat16(s[(size_t)i * 4 * 65536]);
  }
  __syncthreads();
  {
    int cl = tid & 63, hb = tid >> 6;
#pragma unroll
    for (int j = 0; j < 16; ++j) {
      int hwl = hb + j * 4;
      int hw = hwb + hwl;
      int h = hw >> 8, w = hw & 255;
      int sw = swoff + ((h >> 3) << 5) + (w >> 3);
      int t = ((h & 7) << 3) + (w & 7);
      dst[((size_t)(sw * 64 + t) << 8) + c0 + cl] = T[cl][hwl];
    }
  }
}

// ---------------------------------------------------------------------------
// T2: kv stripe transpose: f32 NCHW (one batch) -> bf16 NHWC rows.
// ---------------------------------------------------------------------------
__global__ __launch_bounds__(256) void t_nhwc_k(const float* __restrict__ src,
                                                bf16* __restrict__ dst, int hw0) {
  __shared__ bf16 T[64][66];
  int tile = blockIdx.x;
  int c0 = (tile & 3) << 6;
  int hwoff = (tile >> 2) << 6;
  int tid = threadIdx.x;
  {
    int hwl = tid & 63, cb = tid >> 6;
    const float* s = src + (size_t)(c0 + cb) * 65536 + hw0 + hwoff + hwl;
#pragma unroll
    for (int i = 0; i < 16; ++i)
      T[cb + i * 4][hwl] = __float2bfloat16(s[(size_t)i * 4 * 65536]);
  }
  __syncthreads();
  {
    int cl = tid & 63, hb = tid >> 6;
#pragma unroll
    for (int j = 0; j < 16; ++j) {
      int hwl = hb + j * 4;
      dst[((size_t)(hwoff + hwl) << 8) + c0 + cl] = T[cl][hwl];
    }
  }
}

// ---------------------------------------------------------------------------
// K1: depthwise 3x3 conv from NHWC bf16 stripe, fused window gather.
// ---------------------------------------------------------------------------
__global__ __launch_bounds__(256) void conv_k(const bf16* __restrict__ kvbC,
                                              const float* __restrict__ wdw,
                                              bf16* __restrict__ kvw,
                                              int wid_base, int cw, int psw0,
                                              int h_start) {
  int bid = blockIdx.x;
  int swc = (bid & 7) * (cw >> 3) + (bid >> 3);
  int wid = wid_base + swc;
  int rem = wid & 1023, wh = rem >> 5, ww = rem & 31;
  int h0 = wh * 8, w0 = ww * 8;
  int osw = psw0 + swc;
  int c = threadIdx.x;
  float wr[9];
#pragma unroll
  for (int q = 0; q < 9; ++q) wr[q] = wdw[c * 9 + q];
  const bool wlo = (w0 > 0), whi = (w0 < 248);  // wave-uniform

  float rows[3][10];
  auto load_row = [&](int gh, float* r) {
    if (gh >= 0 && gh < 256) {  // wave-uniform
      const bf16* rp = kvbC + ((size_t)((gh - h_start) * 256 + w0) << 8) + c;
      r[0] = wlo ? __bfloat162float(rp[-256]) : 0.f;
#pragma unroll
      for (int s = 1; s <= 8; ++s) r[s] = __bfloat162float(rp[(s - 1) * 256]);
      r[9] = whi ? __bfloat162float(rp[8 * 256]) : 0.f;
    } else {
#pragma unroll
      for (int e = 0; e < 10; ++e) r[e] = 0.f;
    }
  };

  load_row(h0 - 1, rows[0]);
  load_row(h0, rows[1]);
#pragma unroll
  for (int i = 0; i < 8; ++i) {
    load_row(h0 + i + 1, rows[(i + 2) % 3]);
#pragma unroll
    for (int j = 0; j < 8; ++j) {
      float acc = 0.f;
#pragma unroll
      for (int di = 0; di < 3; ++di) {
        const float* rp = rows[(i + di) % 3];
        acc = __builtin_fmaf(wr[di * 3 + 0], rp[j], acc);
        acc = __builtin_fmaf(wr[di * 3 + 1], rp[j + 1], acc);
        acc = __builtin_fmaf(wr[di * 3 + 2], rp[j + 2], acc);
      }
      kvw[((size_t)(osw * 64 + i * 8 + j) << 8) + c] = __float2bfloat16(acc);
    }
  }
}

// ---------------------------------------------------------------------------
// K2: combined kv projection GEMM, 512 threads / 8 waves per block.
// Waves 0-3: k = x@Wk (normal MFMA, D[token][c]) written IN-PLACE over kvw.
// Waves 4-7: v = x@Wv with SWAPPED operands (D[vdim][token]) -> vT direct.
// In-place is safe: __syncthreads() after the K-loop guarantees all A-loads
// (into registers) retired before any wave overwrites kvw.
// ---------------------------------------------------------------------------
__global__ __launch_bounds__(512) void kv_gemm_k(bf16* kvw /*in: x, out: k*/,
                                                 const bf16* __restrict__ wkvT,
                                                 const float* __restrict__ bkv,
                                                 bf16* __restrict__ vT_s, int nw) {
  int bid = blockIdx.x;
  int sw = (bid & 7) * (nw >> 3) + (bid >> 3);
  int tid = threadIdx.x;
  int wave = tid >> 6, lane = tid & 63, quad = lane >> 4, l16 = lane & 15;
  bool isv = wave >= 4;
  int wv = wave & 3;
  int n0 = (isv ? 256 : 0) + wv * 64;
  bf16* A = kvw + ((size_t)sw << 14);
  f32x4 zero4 = {0.f, 0.f, 0.f, 0.f};
  f32x4 acc[4][4];
  for (int mt = 0; mt < 4; ++mt)
    for (int nt = 0; nt < 4; ++nt) acc[mt][nt] = zero4;
  if (!isv) {
    for (int k0 = 0; k0 < 256; k0 += 32) {
      bf16x8 a[4], bb[4];
      for (int mt = 0; mt < 4; ++mt)
        a[mt] = *(const bf16x8*)&A[(size_t)(mt * 16 + l16) * 256 + k0 + quad * 8];
      for (int nt = 0; nt < 4; ++nt)
        bb[nt] = *(const bf16x8*)&wkvT[(size_t)(n0 + nt * 16 + l16) * 256 + k0 + quad * 8];
      for (int mt = 0; mt < 4; ++mt)
        for (int nt = 0; nt < 4; ++nt) acc[mt][nt] = MFMA(a[mt], bb[nt], acc[mt][nt]);
    }
  } else {
    for (int k0 = 0; k0 < 256; k0 += 32) {
      bf16x8 a[4], bb[4];
      for (int mt = 0; mt < 4; ++mt)
        a[mt] = *(const bf16x8*)&A[(size_t)(mt * 16 + l16) * 256 + k0 + quad * 8];
      for (int nt = 0; nt < 4; ++nt)
        bb[nt] = *(const bf16x8*)&wkvT[(size_t)(n0 + nt * 16 + l16) * 256 + k0 + quad * 8];
      for (int mt = 0; mt < 4; ++mt)
        for (int nt = 0; nt < 4; ++nt) acc[mt][nt] = MFMA(bb[nt], a[mt], acc[mt][nt]);
    }
  }
  __syncthreads();  // all A-loads retired; in-place overwrite now safe
  if (!isv) {  // k: D[token][c], token=(quad,r), c=l16
    for (int nt = 0; nt < 4; ++nt) {
      int n = n0 + nt * 16 + l16;
      float bias = bkv[n];
      for (int mt = 0; mt < 4; ++mt) {
        int mb = mt * 16 + quad * 4;
        for (int r = 0; r < 4; ++r)
          A[((size_t)(mb + r) << 8) + n] = __float2bfloat16(acc[mt][nt][r] + bias);
      }
    }
  } else {  // v swapped: D[vdim][token], vdim=(quad,r), token=l16
    int base = n0 - 256;
    for (int nt = 0; nt < 4; ++nt) {
      for (int r = 0; r < 4; ++r) {
        int vd = base + nt * 16 + quad * 4 + r;
        float bias = bkv[256 + vd];
        for (int mt = 0; mt < 4; ++mt)
          vT_s[((size_t)(sw * 256 + vd) << 6) + mt * 16 + l16] =
              __float2bfloat16(acc[mt][nt][r] + bias);
      }
    }
  }
}

// ---------------------------------------------------------------------------
// K3: q projection GEMM from window-major qwM. LDS-free direct A reads.
// ---------------------------------------------------------------------------
__global__ __launch_bounds__(256) void q_gemm_k(const bf16* __restrict__ qwM,
                                                const bf16* __restrict__ wqT,
                                                const float* __restrict__ bq,
                                                bf16* __restrict__ q_s, int nw) {
  int bid = blockIdx.x;
  int sw = (bid & 7) * (nw >> 3) + (bid >> 3);
  int tid = threadIdx.x;
  int wave = tid >> 6, lane = tid & 63, quad = lane >> 4, l16 = lane & 15;
  int n0 = wave * 64;
  const bf16* A = qwM + ((size_t)sw << 14);
  f32x4 zero4 = {0.f, 0.f, 0.f, 0.f};
  f32x4 acc[4][4];
  for (int mt = 0; mt < 4; ++mt)
    for (int nt = 0; nt < 4; ++nt) acc[mt][nt] = zero4;
  for (int k0 = 0; k0 < 256; k0 += 32) {
    bf16x8 a[4], bb[4];
    for (int mt = 0; mt < 4; ++mt)
      a[mt] = *(const bf16x8*)&A[(size_t)(mt * 16 + l16) * 256 + k0 + quad * 8];
    for (int nt = 0; nt < 4; ++nt)
      bb[nt] = *(const bf16x8*)&wqT[(size_t)(n0 + nt * 16 + l16) * 256 + k0 + quad * 8];
    for (int mt = 0; mt < 4; ++mt)
      for (int nt = 0; nt < 4; ++nt) acc[mt][nt] = MFMA(a[mt], bb[nt], acc[mt][nt]);
  }
  const float scale = 0.1767766952966369f;  // 32^-0.5
  for (int nt = 0; nt < 4; ++nt) {
    int n = n0 + nt * 16 + l16;
    float bias = bq[n];
    for (int mt = 0; mt < 4; ++mt) {
      int mb = mt * 16 + quad * 4;
      for (int r = 0; r < 4; ++r)
        q_s[((size_t)(sw * 64 + mb + r) << 8) + n] =
            __float2bfloat16((acc[mt][nt][r] + bias) * scale);
    }
  }
}

// ---------------------------------------------------------------------------
// K4: windowed attention. wave w handles heads {w, w+4}. a_out aliases k_s
// (no __restrict__ on those two!). Safe: each 32-col head block is
// read-then-written by exactly one wave, and hi=0 writes (cols 0..127) are
// disjoint from hi=1 reads (cols 128..255).
// ---------------------------------------------------------------------------
__global__ __launch_bounds__(256) void attn_k(const bf16* __restrict__ q_s,
                                              const bf16* k_s,
                                              const bf16* __restrict__ vT_s,
                                              bf16* a_out, int nw) {
  __shared__ __align__(16) bf16 P[4 * 64 * 72];
  int bid = blockIdx.x;
  int sw = (bid & 7) * (nw >> 3) + (bid >> 3);
  int tid = threadIdx.x, wave = tid >> 6, lane = tid & 63, quad = lane >> 4, l16 = lane & 15;
  const bf16* qw = q_s + ((size_t)sw << 14);
  const bf16* kw = k_s + ((size_t)sw << 14);
  const bf16* vw = vT_s + ((size_t)sw << 14);
  bf16* ow = a_out + ((size_t)sw << 14);
  bf16* Pw = P + wave * 64 * 72;
  f32x4 zero4 = {0.f, 0.f, 0.f, 0.f};
  for (int hi = 0; hi < 2; ++hi) {
    int co = (wave + hi * 4) * 32;  // head channel offset
    f32x4 s[4][4];
    for (int mt = 0; mt < 4; ++mt)
      for (int nt = 0; nt < 4; ++nt) s[mt][nt] = zero4;
    {
      bf16x8 a[4], bb[4];
      for (int mt = 0; mt < 4; ++mt)
        a[mt] = *(const bf16x8*)&qw[(size_t)(mt * 16 + l16) * 256 + co + quad * 8];
      for (int nt = 0; nt < 4; ++nt)
        bb[nt] = *(const bf16x8*)&kw[(size_t)(nt * 16 + l16) * 256 + co + quad * 8];
      for (int mt = 0; mt < 4; ++mt)
        for (int nt = 0; nt < 4; ++nt) s[mt][nt] = MFMA(a[mt], bb[nt], s[mt][nt]);
    }
    float rsum[4][4];
    for (int mt = 0; mt < 4; ++mt) {
      for (int r = 0; r < 4; ++r) {
        float m = s[mt][0][r];
        for (int nt = 1; nt < 4; ++nt) m = fmaxf(m, s[mt][nt][r]);
        m = fmaxf(m, __shfl_xor(m, 1, 64));
        m = fmaxf(m, __shfl_xor(m, 2, 64));
        m = fmaxf(m, __shfl_xor(m, 4, 64));
        m = fmaxf(m, __shfl_xor(m, 8, 64));
        float sum = 0.f;
        for (int nt = 0; nt < 4; ++nt) {
          float e = __expf(s[mt][nt][r] - m);
          s[mt][nt][r] = e;
          sum += e;
        }
        sum += __shfl_xor(sum, 1, 64);
        sum += __shfl_xor(sum, 2, 64);
        sum += __shfl_xor(sum, 4, 64);
        sum += __shfl_xor(sum, 8, 64);
        rsum[mt][r] = sum;
      }
    }
    for (int mt = 0; mt < 4; ++mt)
      for (int nt = 0; nt < 4; ++nt)
        for (int r = 0; r < 4; ++r)
          Pw[(mt * 16 + quad * 4 + r) * 72 + nt * 16 + l16] =
              __float2bfloat16(s[mt][nt][r]);
    __syncthreads();
    f32x4 o[4][2];
    for (int mt = 0; mt < 4; ++mt)
      for (int nt = 0; nt < 2; ++nt) o[mt][nt] = zero4;
    for (int kk = 0; kk < 64; kk += 32) {
      bf16x8 pa[4], vb[2];
      for (int mt = 0; mt < 4; ++mt)
        pa[mt] = *(const bf16x8*)&Pw[(mt * 16 + l16) * 72 + kk + quad * 8];
      for (int nt = 0; nt < 2; ++nt)
        vb[nt] = *(const bf16x8*)&vw[(size_t)(co + nt * 16 + l16) * 64 + kk + quad * 8];
      for (int mt = 0; mt < 4; ++mt)
        for (int nt = 0; nt < 2; ++nt) o[mt][nt] = MFMA(pa[mt], vb[nt], o[mt][nt]);
    }
    for (int mt = 0; mt < 4; ++mt) {
      int mb = mt * 16 + quad * 4;
      for (int nt = 0; nt < 2; ++nt)
        for (int r = 0; r < 4; ++r)
          ow[((size_t)(mb + r) << 8) + co + nt * 16 + l16] =
              __float2bfloat16(o[mt][nt][r] / rsum[mt][r]);
    }
    __syncthreads();
  }
}

// ---------------------------------------------------------------------------
// K5: out projection -> window-major f32 Wout[psw][t][n]. Stores are
// 64B-aligned full sectors (16 consecutive channels per 16 lanes).
// ---------------------------------------------------------------------------
__global__ __launch_bounds__(256) void oproj_k(const bf16* __restrict__ a_out,
                                               const bf16* __restrict__ wpT,
                                               const float* __restrict__ bp,
                                               float* __restrict__ Wout, int nw) {
  int bid = blockIdx.x;
  int sw = (bid & 7) * (nw >> 3) + (bid >> 3);
  int tid = threadIdx.x, wave = tid >> 6, lane = tid & 63, quad = lane >> 4, l16 = lane & 15;
  const bf16* aw = a_out + ((size_t)sw << 14);
  int n0 = wave * 64;
  f32x4 zero4 = {0.f, 0.f, 0.f, 0.f};
  f32x4 acc[4][4];
  for (int mt = 0; mt < 4; ++mt)
    for (int nt = 0; nt < 4; ++nt) acc[mt][nt] = zero4;
  for (int k0 = 0; k0 < 256; k0 += 32) {
    bf16x8 a[4], bb[4];
    for (int mt = 0; mt < 4; ++mt)
      a[mt] = *(const bf16x8*)&aw[(size_t)(mt * 16 + l16) * 256 + k0 + quad * 8];
    for (int nt = 0; nt < 4; ++nt)
      bb[nt] = *(const bf16x8*)&wpT[(size_t)(n0 + nt * 16 + l16) * 256 + k0 + quad * 8];
    for (int mt = 0; mt < 4; ++mt)
      for (int nt = 0; nt < 4; ++nt) acc[mt][nt] = MFMA(a[mt], bb[nt], acc[mt][nt]);
  }
  for (int nt = 0; nt < 4; ++nt) {
    int n = n0 + nt * 16 + l16;
    float bias = bp[n];
    for (int mt = 0; mt < 4; ++mt) {
      int mb = mt * 16 + quad * 4;
      for (int r = 0; r < 4; ++r)
        Wout[((size_t)(sw * 64 + mb + r) << 8) + n] = acc[mt][nt][r] + bias;
    }
  }
}

// ---------------------------------------------------------------------------
// T3: window-major f32 Wout -> NCHW f32 out. LDS 64x65 tile; reads 256B
// coalesced (lanes along c), writes 256B coalesced (lanes along w).
// ---------------------------------------------------------------------------
__global__ __launch_bounds__(256) void t_out_k(const float* __restrict__ Wout,
                                               float* __restrict__ out,
                                               int b, int h0c, int wbP) {
  __shared__ float T[64][65];
  int bid = blockIdx.x;
  int c0 = (bid & 3) << 6;
  int wseg = ((bid >> 2) & 3) << 6;
  int h = h0c + (bid >> 4);
  int tid = threadIdx.x;
  int swrow_base = b * 1024 + ((h >> 3) << 5) - wbP;
  int trow = (h & 7) << 3;
  {
    int cl = tid & 63, hb = tid >> 6;
#pragma unroll
    for (int j = 0; j < 16; ++j) {
      int wl = hb + j * 4;
      int w = wseg + wl;
      int psw = swrow_base + (w >> 3);
      int t = trow + (w & 7);
      T[wl][cl] = Wout[((size_t)(psw * 64 + t) << 8) + c0 + cl];
    }
  }
  __syncthreads();
  {
    int wl = tid & 63, cb = tid >> 6;
    float* chan = out + ((size_t)(b * 256 + c0) << 16) + (size_t)h * 256 + wseg;
#pragma unroll
    for (int j = 0; j < 16; ++j) {
      int c = cb + j * 4;
      chan[((size_t)c << 16) + wl] = T[wl][c];
    }
  }
}

// ---------------------------------------------------------------------------
extern "C" void kernel_launch(void* const* d_in, const int* in_sizes, int n_in,
                              void* d_out, int out_size, void* d_ws, size_t ws_size,
                              hipStream_t stream) {
  const float* qf  = (const float*)d_in[0];
  const float* kvf = (const float*)d_in[1];
  const float* wdw = (const float*)d_in[2];
  const float* wq  = (const float*)d_in[3];
  const float* bq  = (const float*)d_in[4];
  const float* wkv = (const float*)d_in[5];
  const float* bkv = (const float*)d_in[6];
  const float* wp  = (const float*)d_in[7];
  const float* bp  = (const float*)d_in[8];
  float* out = (float*)d_out;

  bf16* wqT  = (bf16*)d_ws;
  bf16* wkvT = wqT + 65536;
  bf16* wpT  = wkvT + 131072;
  bf16* bufs = wpT + 65536;
  const size_t welems = 65536 + 131072 + 65536;
  const size_t skelems = (size_t)130 * 65536;  // NHWC stripe: 128 rows + 2 halo

  // Slots: SK (conv stripe) | S0 | S1 | S2, each nw*32KB.
  // Lifetimes: qwM->S0, q_s->S1, kvw->S2 (k_s in-place), vT->S0,
  // a_out->S2 (alias k_s), Wout(f32) overlays S0+S1 (both dead after attn).
  int passes = 1;
  while (passes < 32) {
    size_t nw_ = 2048 / passes;
    size_t elems = welems + skelems + 3 * nw_ * 16384;
    if (elems * 2 <= ws_size) break;
    passes <<= 1;
  }
  int nw = 2048 / passes;
  int cw = nw < 512 ? nw : 512;  // chunk: <=512 windows, single batch, 128 h-rows
  size_t sz = (size_t)nw * 16384;
  bf16* SK = bufs;
  bf16* S0 = SK + skelems;
  bf16* S1 = S0 + sz;
  bf16* S2 = S1 + sz;

  wtrans_k<<<1024, 256, 0, stream>>>(wq, wkv, wp, wqT, wkvT, wpT);

  for (int p = 0; p < passes; ++p) {
    int wbP = p * nw;
    int nch = nw / cw;
    int nh = (cw >> 5) * 8;  // h-rows per chunk
    // --- q path: gather-transpose then projection ---
    for (int ch = 0; ch < nch; ++ch) {
      int wbC = wbP + ch * cw;
      int b = wbC >> 10;
      int h0 = ((wbC & 1023) >> 5) * 8;
      t_winq_k<<<cw * 4, 256, 0, stream>>>(qf + ((size_t)b << 24), S0, h0 * 256,
                                           b * 1024 - wbP);
    }
    q_gemm_k<<<nw, 256, 0, stream>>>(S0, wqT, bq, S1, nw);
    // --- kv path: NHWC stripe, conv, combined kv projection ---
    for (int ch = 0; ch < nch; ++ch) {
      int wbC = wbP + ch * cw;
      int b = wbC >> 10;
      int h0 = ((wbC & 1023) >> 5) * 8;
      int psw0 = wbC - wbP;
      int gh_lo = h0 > 0 ? h0 - 1 : 0;
      int gh_hi = (h0 + nh + 1 < 256) ? h0 + nh + 1 : 256;
      int rows = gh_hi - gh_lo;
      int h_start = h0 - 1;
      bf16* tdst = SK + (size_t)(gh_lo - h_start) * 65536;
      t_nhwc_k<<<rows * 16, 256, 0, stream>>>(kvf + ((size_t)b << 24), tdst,
                                              gh_lo * 256);
      conv_k<<<cw, 256, 0, stream>>>(SK, wdw, S2, wbC, cw, psw0, h_start);
    }
    kv_gemm_k<<<nw, 512, 0, stream>>>(S2, wkvT, bkv, S0, nw);
    // --- attention, out-projection, reverse transform ---
    attn_k<<<nw, 256, 0, stream>>>(S1, S2, S0, S2, nw);
    oproj_k<<<nw, 256, 0, stream>>>(S2, wpT, bp, (float*)S0, nw);
    for (int ch = 0; ch < nch; ++ch) {
      int wbC = wbP + ch * cw;
      int b = wbC >> 10;
      int h0 = ((wbC & 1023) >> 5) * 8;
      t_out_k<<<nh * 16, 256, 0, stream>>>((const float*)S0, out, b, h0, wbP);
    }
  }
}

// Round 5
// 620.681 us; speedup vs baseline: 1.2844x; 1.2844x over previous
//
#include <hip/hip_runtime.h>
#include <hip/hip_bf16.h>
#include <cstdint>
#include <cstddef>

typedef __hip_bfloat16 bf16;
typedef short bf16x8 __attribute__((ext_vector_type(8)));
typedef float f32x4 __attribute__((ext_vector_type(4)));

#define MFMA(a, b, c) __builtin_amdgcn_mfma_f32_16x16x32_bf16((a), (b), (c), 0, 0, 0)

// ---------------------------------------------------------------------------
// K0: all three weight transposes in one launch (grid 1024).
// ---------------------------------------------------------------------------
__global__ __launch_bounds__(256) void wtrans_k(const float* __restrict__ wq,
                                                const float* __restrict__ wkv,
                                                const float* __restrict__ wp,
                                                bf16* __restrict__ wqT,
                                                bf16* __restrict__ wkvT,
                                                bf16* __restrict__ wpT) {
  int idx = blockIdx.x * 256 + threadIdx.x;
  if (idx < 65536) {
    int n = idx >> 8, k = idx & 255;
    wqT[idx] = __float2bfloat16(wq[k * 256 + n]);
  } else if (idx < 196608) {
    int i = idx - 65536;
    int n = i >> 8, k = i & 255;
    wkvT[i] = __float2bfloat16(wkv[k * 512 + n]);
  } else {
    int i = idx - 196608;
    int n = i >> 8, k = i & 255;
    wpT[i] = __float2bfloat16(wp[k * 256 + n]);
  }
}

// ---------------------------------------------------------------------------
// T1: q gather-transpose: f32 NCHW (one batch) -> bf16 WINDOW-MAJOR qwM[sw][t][c].
// ---------------------------------------------------------------------------
__global__ __launch_bounds__(256) void t_winq_k(const float* __restrict__ src,
                                                bf16* __restrict__ dst,
                                                int hw0, int swoff) {
  __shared__ bf16 T[64][66];
  int tile = blockIdx.x;
  int c0 = (tile & 3) << 6;
  int hwb = hw0 + ((tile >> 2) << 6);
  int tid = threadIdx.x;
  {
    int hwl = tid & 63, cb = tid >> 6;
    const float* s = src + (size_t)(c0 + cb) * 65536 + hwb + hwl;
#pragma unroll
    for (int i = 0; i < 16; ++i)
      T[cb + i * 4][hwl] = __float2bfloat16(s[(size_t)i * 4 * 65536]);
  }
  __syncthreads();
  {
    int cl = tid & 63, hb = tid >> 6;
#pragma unroll
    for (int j = 0; j < 16; ++j) {
      int hwl = hb + j * 4;
      int hw = hwb + hwl;
      int h = hw >> 8, w = hw & 255;
      int sw = swoff + ((h >> 3) << 5) + (w >> 3);
      int t = ((h & 7) << 3) + (w & 7);
      dst[((size_t)(sw * 64 + t) << 8) + c0 + cl] = T[cl][hwl];
    }
  }
}

// ---------------------------------------------------------------------------
// T2: full-image transpose: f32 NCHW (one batch) -> bf16 NHWC (one batch).
// grid 4096.
// ---------------------------------------------------------------------------
__global__ __launch_bounds__(256) void t_nhwc_k(const float* __restrict__ src,
                                                bf16* __restrict__ dst) {
  __shared__ bf16 T[64][66];
  int tile = blockIdx.x;
  int c0 = (tile & 3) << 6;
  int hwoff = (tile >> 2) << 6;
  int tid = threadIdx.x;
  {
    int hwl = tid & 63, cb = tid >> 6;
    const float* s = src + (size_t)(c0 + cb) * 65536 + hwoff + hwl;
#pragma unroll
    for (int i = 0; i < 16; ++i)
      T[cb + i * 4][hwl] = __float2bfloat16(s[(size_t)i * 4 * 65536]);
  }
  __syncthreads();
  {
    int cl = tid & 63, hb = tid >> 6;
#pragma unroll
    for (int j = 0; j < 16; ++j) {
      int hwl = hb + j * 4;
      dst[((size_t)(hwoff + hwl) << 8) + c0 + cl] = T[cl][hwl];
    }
  }
}

// ---------------------------------------------------------------------------
// K1: FUSED conv + kv projection. One block per window, 256 threads.
// Phase A: depthwise 3x3 conv from full-image NHWC (coalesced, lanes along c),
//          results straight to LDS X[64][264] (bf16).
// Phase B: 4 waves; each does k-cols n0=wave*64 (normal MFMA, D[token][c])
//          then v-cols (swapped MFMA, D[vdim][token] -> coalesced vT write).
// ---------------------------------------------------------------------------
__global__ __launch_bounds__(256) void convkv_k(const bf16* __restrict__ SK,
                                                const float* __restrict__ wdw,
                                                const bf16* __restrict__ wkvT,
                                                const float* __restrict__ bkv,
                                                bf16* __restrict__ k_s,
                                                bf16* __restrict__ vT_s,
                                                int wid_base, int cnt, int psw0,
                                                int nwtot) {
  __shared__ __align__(16) bf16 X[64 * 264];
  int bid = blockIdx.x;
  int swc = (bid & 7) * (cnt >> 3) + (bid >> 3);
  int sw = psw0 + swc;
  int wid = wid_base + swc;
  int rem = wid & 1023, wh = rem >> 5, ww = rem & 31;
  int h0 = wh * 8, w0 = ww * 8;
  int tid = threadIdx.x;
  {  // phase A: conv, thread = channel
    int c = tid;
    float wr[9];
#pragma unroll
    for (int q = 0; q < 9; ++q) wr[q] = wdw[c * 9 + q];
    const bool wlo = (w0 > 0), whi = (w0 < 248);
    float rows[3][10];
    auto load_row = [&](int gh, float* r) {
      if (gh >= 0 && gh < 256) {
        const bf16* rp = SK + ((size_t)(gh * 256 + w0) << 8) + c;
        r[0] = wlo ? __bfloat162float(rp[-256]) : 0.f;
#pragma unroll
        for (int s = 1; s <= 8; ++s) r[s] = __bfloat162float(rp[(s - 1) * 256]);
        r[9] = whi ? __bfloat162float(rp[8 * 256]) : 0.f;
      } else {
#pragma unroll
        for (int e = 0; e < 10; ++e) r[e] = 0.f;
      }
    };
    load_row(h0 - 1, rows[0]);
    load_row(h0, rows[1]);
#pragma unroll
    for (int i = 0; i < 8; ++i) {
      load_row(h0 + i + 1, rows[(i + 2) % 3]);
#pragma unroll
      for (int j = 0; j < 8; ++j) {
        float acc = 0.f;
#pragma unroll
        for (int di = 0; di < 3; ++di) {
          const float* rp = rows[(i + di) % 3];
          acc = __builtin_fmaf(wr[di * 3 + 0], rp[j], acc);
          acc = __builtin_fmaf(wr[di * 3 + 1], rp[j + 1], acc);
          acc = __builtin_fmaf(wr[di * 3 + 2], rp[j + 2], acc);
        }
        X[(i * 8 + j) * 264 + c] = __float2bfloat16(acc);
      }
    }
  }
  __syncthreads();
  int wave = tid >> 6, lane = tid & 63, quad = lane >> 4, l16 = lane & 15;
  int n0 = wave * 64;
  f32x4 zero4 = {0.f, 0.f, 0.f, 0.f};
  f32x4 acc[4][4];
  // ---- k pass (normal MFMA) ----
  for (int mt = 0; mt < 4; ++mt)
    for (int nt = 0; nt < 4; ++nt) acc[mt][nt] = zero4;
  for (int k0 = 0; k0 < 256; k0 += 32) {
    bf16x8 a[4], bb[4];
    for (int mt = 0; mt < 4; ++mt)
      a[mt] = *(const bf16x8*)&X[(mt * 16 + l16) * 264 + k0 + quad * 8];
    for (int nt = 0; nt < 4; ++nt)
      bb[nt] = *(const bf16x8*)&wkvT[(size_t)(n0 + nt * 16 + l16) * 256 + k0 + quad * 8];
    for (int mt = 0; mt < 4; ++mt)
      for (int nt = 0; nt < 4; ++nt) acc[mt][nt] = MFMA(a[mt], bb[nt], acc[mt][nt]);
  }
  for (int nt = 0; nt < 4; ++nt) {
    int n = n0 + nt * 16 + l16;
    float bias = bkv[n];
    for (int mt = 0; mt < 4; ++mt) {
      int mb = mt * 16 + quad * 4;
      for (int r = 0; r < 4; ++r)
        k_s[((size_t)(sw * 64 + mb + r) << 8) + n] =
            __float2bfloat16(acc[mt][nt][r] + bias);
    }
  }
  // ---- v pass (swapped MFMA -> D[vdim][token]) ----
  for (int mt = 0; mt < 4; ++mt)
    for (int nt = 0; nt < 4; ++nt) acc[mt][nt] = zero4;
  for (int k0 = 0; k0 < 256; k0 += 32) {
    bf16x8 a[4], bb[4];
    for (int mt = 0; mt < 4; ++mt)
      a[mt] = *(const bf16x8*)&X[(mt * 16 + l16) * 264 + k0 + quad * 8];
    for (int nt = 0; nt < 4; ++nt)
      bb[nt] = *(const bf16x8*)&wkvT[(size_t)(256 + n0 + nt * 16 + l16) * 256 + k0 + quad * 8];
    for (int mt = 0; mt < 4; ++mt)
      for (int nt = 0; nt < 4; ++nt) acc[mt][nt] = MFMA(bb[nt], a[mt], acc[mt][nt]);
  }
  for (int nt = 0; nt < 4; ++nt) {
    for (int r = 0; r < 4; ++r) {
      int vd = n0 + nt * 16 + quad * 4 + r;
      float bias = bkv[256 + vd];
      for (int mt = 0; mt < 4; ++mt)
        vT_s[((size_t)(sw * 256 + vd) << 6) + mt * 16 + l16] =
            __float2bfloat16(acc[mt][nt][r] + bias);
    }
  }
}

// ---------------------------------------------------------------------------
// K2: FUSED q-projection + attention + out-projection. One block per window.
// LDS: Q[64][264] holds q result, then (col-block aliased) attention output.
//      P[4*64*72] first stages the qwM window, then per-wave P tiles.
// Out-proj writes NCHW f32 directly (rows of 4 w-positions per f32x4 store).
// ---------------------------------------------------------------------------
__global__ __launch_bounds__(256) void fused_k(const bf16* __restrict__ qwM,
                                               const bf16* __restrict__ wqT,
                                               const float* __restrict__ bq,
                                               const bf16* __restrict__ k_s,
                                               const bf16* __restrict__ vT_s,
                                               const bf16* __restrict__ wpT,
                                               const float* __restrict__ bp,
                                               float* __restrict__ out,
                                               int wid_base, int nw) {
  __shared__ __align__(16) bf16 Q[64 * 264];
  __shared__ __align__(16) bf16 P[4 * 64 * 72];
  int bid = blockIdx.x;
  int sw = (bid & 7) * (nw >> 3) + (bid >> 3);
  int wid = wid_base + sw;
  int b = wid >> 10, rem = wid & 1023, wh = rem >> 5, ww = rem & 31;
  int h0 = wh * 8, w0 = ww * 8;
  int tid = threadIdx.x, wave = tid >> 6, lane = tid & 63, quad = lane >> 4, l16 = lane & 15;
  f32x4 zero4 = {0.f, 0.f, 0.f, 0.f};
  {  // stage qwM window into P-area (Xq[64][264])
    int t = tid >> 2, cb = (tid & 3) * 64;
    const bf16* src = &qwM[((size_t)(sw * 64 + t) << 8) + cb];
    bf16* dst = &P[t * 264 + cb];
    for (int i = 0; i < 8; ++i) *(bf16x8*)&dst[i * 8] = *(const bf16x8*)&src[i * 8];
  }
  __syncthreads();
  // ---- phase 1: q = (x@wq + bq) * scale -> Q LDS ----
  {
    const bf16* Xq = P;
    int n0 = wave * 64;
    f32x4 acc[4][4];
    for (int mt = 0; mt < 4; ++mt)
      for (int nt = 0; nt < 4; ++nt) acc[mt][nt] = zero4;
    for (int k0 = 0; k0 < 256; k0 += 32) {
      bf16x8 a[4], bb[4];
      for (int mt = 0; mt < 4; ++mt)
        a[mt] = *(const bf16x8*)&Xq[(mt * 16 + l16) * 264 + k0 + quad * 8];
      for (int nt = 0; nt < 4; ++nt)
        bb[nt] = *(const bf16x8*)&wqT[(size_t)(n0 + nt * 16 + l16) * 256 + k0 + quad * 8];
      for (int mt = 0; mt < 4; ++mt)
        for (int nt = 0; nt < 4; ++nt) acc[mt][nt] = MFMA(a[mt], bb[nt], acc[mt][nt]);
    }
    const float scale = 0.1767766952966369f;  // 32^-0.5
    for (int nt = 0; nt < 4; ++nt) {
      int n = n0 + nt * 16 + l16;
      float bias = bq[n];
      for (int mt = 0; mt < 4; ++mt) {
        int mb = mt * 16 + quad * 4;
        for (int r = 0; r < 4; ++r)
          Q[(mb + r) * 264 + n] = __float2bfloat16((acc[mt][nt][r] + bias) * scale);
      }
    }
  }
  __syncthreads();  // Q ready; P-area (qwM stage) now dead
  // ---- phase 2: attention; O overwrites Q col-blocks (disjoint per hi) ----
  const bf16* kw = k_s + ((size_t)sw << 14);
  const bf16* vw = vT_s + ((size_t)sw << 14);
  bf16* Pw = P + wave * 64 * 72;
  for (int hi = 0; hi < 2; ++hi) {
    int co = (wave + hi * 4) * 32;
    f32x4 s[4][4];
    for (int mt = 0; mt < 4; ++mt)
      for (int nt = 0; nt < 4; ++nt) s[mt][nt] = zero4;
    {
      bf16x8 a[4], bb[4];
      for (int mt = 0; mt < 4; ++mt)
        a[mt] = *(const bf16x8*)&Q[(mt * 16 + l16) * 264 + co + quad * 8];
      for (int nt = 0; nt < 4; ++nt)
        bb[nt] = *(const bf16x8*)&kw[(size_t)(nt * 16 + l16) * 256 + co + quad * 8];
      for (int mt = 0; mt < 4; ++mt)
        for (int nt = 0; nt < 4; ++nt) s[mt][nt] = MFMA(a[mt], bb[nt], s[mt][nt]);
    }
    float rsum[4][4];
    for (int mt = 0; mt < 4; ++mt) {
      for (int r = 0; r < 4; ++r) {
        float m = s[mt][0][r];
        for (int nt = 1; nt < 4; ++nt) m = fmaxf(m, s[mt][nt][r]);
        m = fmaxf(m, __shfl_xor(m, 1, 64));
        m = fmaxf(m, __shfl_xor(m, 2, 64));
        m = fmaxf(m, __shfl_xor(m, 4, 64));
        m = fmaxf(m, __shfl_xor(m, 8, 64));
        float sum = 0.f;
        for (int nt = 0; nt < 4; ++nt) {
          float e = __expf(s[mt][nt][r] - m);
          s[mt][nt][r] = e;
          sum += e;
        }
        sum += __shfl_xor(sum, 1, 64);
        sum += __shfl_xor(sum, 2, 64);
        sum += __shfl_xor(sum, 4, 64);
        sum += __shfl_xor(sum, 8, 64);
        rsum[mt][r] = sum;
      }
    }
    for (int mt = 0; mt < 4; ++mt)
      for (int nt = 0; nt < 4; ++nt)
        for (int r = 0; r < 4; ++r)
          Pw[(mt * 16 + quad * 4 + r) * 72 + nt * 16 + l16] =
              __float2bfloat16(s[mt][nt][r]);
    __syncthreads();
    f32x4 o[4][2];
    for (int mt = 0; mt < 4; ++mt)
      for (int nt = 0; nt < 2; ++nt) o[mt][nt] = zero4;
    for (int kk = 0; kk < 64; kk += 32) {
      bf16x8 pa[4], vb[2];
      for (int mt = 0; mt < 4; ++mt)
        pa[mt] = *(const bf16x8*)&Pw[(mt * 16 + l16) * 72 + kk + quad * 8];
      for (int nt = 0; nt < 2; ++nt)
        vb[nt] = *(const bf16x8*)&vw[(size_t)(co + nt * 16 + l16) * 64 + kk + quad * 8];
      for (int mt = 0; mt < 4; ++mt)
        for (int nt = 0; nt < 2; ++nt) o[mt][nt] = MFMA(pa[mt], vb[nt], o[mt][nt]);
    }
    for (int mt = 0; mt < 4; ++mt) {
      int mb = mt * 16 + quad * 4;
      for (int nt = 0; nt < 2; ++nt)
        for (int r = 0; r < 4; ++r)
          Q[(mb + r) * 264 + co + nt * 16 + l16] =
              __float2bfloat16(o[mt][nt][r] / rsum[mt][r]);
    }
    __syncthreads();
  }
  // ---- phase 3: out-projection from Q (attn-out) -> NCHW f32 ----
  {
    int n0 = wave * 64;
    f32x4 acc[4][4];
    for (int mt = 0; mt < 4; ++mt)
      for (int nt = 0; nt < 4; ++nt) acc[mt][nt] = zero4;
    for (int k0 = 0; k0 < 256; k0 += 32) {
      bf16x8 a[4], bb[4];
      for (int mt = 0; mt < 4; ++mt)
        a[mt] = *(const bf16x8*)&Q[(mt * 16 + l16) * 264 + k0 + quad * 8];
      for (int nt = 0; nt < 4; ++nt)
        bb[nt] = *(const bf16x8*)&wpT[(size_t)(n0 + nt * 16 + l16) * 256 + k0 + quad * 8];
      for (int mt = 0; mt < 4; ++mt)
        for (int nt = 0; nt < 4; ++nt) acc[mt][nt] = MFMA(a[mt], bb[nt], acc[mt][nt]);
    }
    for (int nt = 0; nt < 4; ++nt) {
      int n = n0 + nt * 16 + l16;
      float bias = bp[n];
      float* chan = out + ((size_t)(b * 256 + n) << 16);
      for (int mt = 0; mt < 4; ++mt) {
        int row_i = mt * 2 + (quad >> 1);
        int j0 = (quad & 1) * 4;
        f32x4 v4;
        for (int r = 0; r < 4; ++r) v4[r] = acc[mt][nt][r] + bias;
        *(f32x4*)&chan[(size_t)(h0 + row_i) * 256 + w0 + j0] = v4;
      }
    }
  }
}

// ---------------------------------------------------------------------------
extern "C" void kernel_launch(void* const* d_in, const int* in_sizes, int n_in,
                              void* d_out, int out_size, void* d_ws, size_t ws_size,
                              hipStream_t stream) {
  const float* qf  = (const float*)d_in[0];
  const float* kvf = (const float*)d_in[1];
  const float* wdw = (const float*)d_in[2];
  const float* wq  = (const float*)d_in[3];
  const float* bq  = (const float*)d_in[4];
  const float* wkv = (const float*)d_in[5];
  const float* bkv = (const float*)d_in[6];
  const float* wp  = (const float*)d_in[7];
  const float* bp  = (const float*)d_in[8];
  float* out = (float*)d_out;

  bf16* wqT  = (bf16*)d_ws;
  bf16* wkvT = wqT + 65536;
  bf16* wpT  = wkvT + 131072;
  bf16* bufs = wpT + 65536;
  const size_t welems = 65536 + 131072 + 65536;
  const size_t skelems = (size_t)256 * 256 * 256;  // full-image NHWC, one batch

  int passes = 1;
  while (passes < 32) {
    size_t nw_ = 2048 / passes;
    size_t elems = welems + skelems + 3 * nw_ * 16384;
    if (elems * 2 <= ws_size) break;
    passes <<= 1;
  }
  int nw = 2048 / passes;
  size_t sz = (size_t)nw * 16384;
  bf16* SK  = bufs;            // NHWC kv image (one batch at a time)
  bf16* qwM = SK + skelems;    // window-major staged q
  bf16* KS  = qwM + sz;        // k
  bf16* VT  = KS + sz;         // vT

  wtrans_k<<<1024, 256, 0, stream>>>(wq, wkv, wp, wqT, wkvT, wpT);

  for (int p = 0; p < passes; ++p) {
    int wbP = p * nw;
    int b0 = wbP >> 10, b1 = (wbP + nw - 1) >> 10;
    // q staging for every batch overlapping this pass
    for (int b = b0; b <= b1; ++b) {
      int s = wbP > b * 1024 ? wbP : b * 1024;
      int e = (wbP + nw) < (b + 1) * 1024 ? (wbP + nw) : (b + 1) * 1024;
      int cnt = e - s;
      int h0 = ((s & 1023) >> 5) * 8;
      t_winq_k<<<cnt * 4, 256, 0, stream>>>(qf + ((size_t)b << 24), qwM,
                                            h0 * 256, b * 1024 - wbP);
    }
    // kv path: per batch, full-image NHWC then fused conv+kv projection
    for (int b = b0; b <= b1; ++b) {
      int s = wbP > b * 1024 ? wbP : b * 1024;
      int e = (wbP + nw) < (b + 1) * 1024 ? (wbP + nw) : (b + 1) * 1024;
      int cnt = e - s;
      t_nhwc_k<<<4096, 256, 0, stream>>>(kvf + ((size_t)b << 24), SK);
      convkv_k<<<cnt, 256, 0, stream>>>(SK, wdw, wkvT, bkv, KS, VT,
                                        s, cnt, s - wbP, nw);
    }
    // fused q-proj + attention + out-proj
    fused_k<<<nw, 256, 0, stream>>>(qwM, wqT, bq, KS, VT, wpT, bp, out, wbP, nw);
  }
}